// Round 15
// baseline (48.474 us; speedup 1.0000x reference)
//
#include <hip/hip_runtime.h>
#include <math.h>

#define B 32
#define T 262144
#define NFR 250
#define NCH 64              // chunks per row
#define CHUNK 4096          // elements per chunk
#define NTHR 256
#define EPT 16              // elements per thread (contiguous ownership)
#define NBLK (B * NCH)      // 2048 blocks

#define STEPF (249.0f / 262143.0f)  // frame step per sample

// d_ws: vals u64[2048] padded to 256 B stride (value==0 -> not ready),
// then the ticket counter. memset clears everything each launch.
#define VSTRIDE 32                       // u64 per slot (256 B)
#define WS_CLEAR (NBLK * 256 + 256)

typedef float v2f __attribute__((ext_vector_type(2)));

// [256][16] f32 tile swizzle: XOR on e bits [3:2] keeps float4 alignment and
// makes per-owner b128 and linear coalesced b128 both bank-conflict-free.
__device__ __forceinline__ int swz16(int t, int e) {
  return t * 16 + (e ^ ((t & 3) << 2));
}

// ===== single-pass ticketed chained-scan + FM chain (RMW-coherent spin) =====
__global__ __launch_bounds__(NTHR, 6) void k_one(
    const float* __restrict__ f0, const float* __restrict__ mod_index,
    const float* __restrict__ freq_ratio, const float* __restrict__ adsr,
    unsigned long long* __restrict__ vals, unsigned int* __restrict__ counter,
    float* __restrict__ out) {
  __shared__ __align__(16) float tile[NTHR * EPT];  // 16 KB output staging
  __shared__ double wsum[NTHR / 64];
  __shared__ double cbsh;
  __shared__ int stk;
  __shared__ float envtab[8][6];  // raw envelope at frames i0s_blk+0..7
  __shared__ float emsh[6];       // 2*sigmoid(mod_index), pre-halved k=0,2

  int t = threadIdx.x, lane = t & 63, wid = t >> 6;

  // ticket: any spinning block's predecessors are guaranteed started
  if (t == 0) stk = (int)atomicAdd(counter, 1u);
  __syncthreads();
  int tk = stk;
  int ch = tk >> 5;   // chunk index within row; low chunks get early tickets
  int row = tk & 31;
  size_t rowOff = (size_t)row * T;

  // ---- issue own 16-element loads first ----
  const float4* fp4 = (const float4*)(f0 + rowOff + ch * CHUNK + t * EPT);
  float4 v4[4];
#pragma unroll
  for (int q = 0; q < 4; ++q) v4[q] = fp4[q];

  // ---- shared envelope table (block spans <4 frames) ----
  int i0_blk = ch * CHUNK;
  int i0s_blk = (int)floorf((float)i0_blk * STEPF);
  if (t < 48) {  // raw envelope at frame i0s_blk + t/6, op t%6
    int fr = t / 6, k = t - 6 * fr;
    int fi = i0s_blk + fr;
    fi = (fi < NFR - 1) ? fi : NFR - 1;
    const float* ap = adsr + row * 11 + k;
    float fl = ap[0], pk = ap[1];
    float a = fmaxf(ap[2], 1e-5f);
    float de = fmaxf(ap[3], 1e-5f);
    float ss = ap[4];
    float r = fmaxf(ap[5], 1e-5f);
    float tt = (float)fi * (1.0f / 249.0f);
    float att = fminf(fmaxf(tt / a, 0.0f), 1.0f);
    float dec = fminf(fmaxf((tt - a) / de, 0.0f), 1.0f);
    float rel = fminf(fmaxf((tt - (1.0f - r)) / r, 0.0f), 1.0f);
    float env = att * (1.0f - (1.0f - ss) * dec) * (1.0f - rel);
    envtab[fr][k] = fl + (pk - fl) * env;
  } else if (t < 54) {
    int k = t - 48;
    float em = 2.0f / (1.0f + expf(-mod_index[row * 6 + k]));
    emsh[k] = (k == 0 || k == 2) ? 0.5f * em : em;  // fold (o3+o1)/2
  }

  // ---- consume loads: relative inclusive prefix ----
  float sv[EPT];
  {
    float a = 0.0f;
#pragma unroll
    for (int q = 0; q < 4; ++q) {
      a += v4[q].x; sv[4 * q] = a;
      a += v4[q].y; sv[4 * q + 1] = a;
      a += v4[q].z; sv[4 * q + 2] = a;
      a += v4[q].w; sv[4 * q + 3] = a;
    }
  }
  double ts = (double)sv[EPT - 1];

  // ---- wave inclusive f64 scan over thread sums ----
  double x = ts;
#pragma unroll
  for (int d = 1; d < 64; d <<= 1) {
    double n = __shfl_up(x, d);
    if (lane >= d) x += n;
  }
  if (lane == 63) wsum[wid] = x;
  __syncthreads();  // wsum + envtab + emsh ready
  double wbase = 0.0, tot = 0.0;
#pragma unroll
  for (int w = 0; w < NTHR / 64; ++w) {
    double s = wsum[w];
    wbase += (w < wid) ? s : 0.0;
    tot += s;
  }

  // ---- publish chunk aggregate (RMW -> device coherence point) ----
  if (t == 0)
    atomicExch(vals + (size_t)tk * VSTRIDE,
               (unsigned long long)__double_as_longlong(tot));

  // ---- lookback: wave 0 polls predecessors with RMW atomics ----
  if (wid == 0) {
    double pv = 0.0;
    if (lane < ch) {
      unsigned long long* slot =
          vals + (size_t)((lane << 5) + row) * VSTRIDE;  // pred ticket < tk
      unsigned long long bits;
      while ((bits = atomicAdd(slot, 0ULL)) == 0ULL)
        __builtin_amdgcn_s_sleep(8);  // ~512 cy backoff; lanes exit as seen
      pv = __longlong_as_double((long long)bits);
    }
#pragma unroll
    for (int d = 32; d > 0; d >>= 1) pv += __shfl_down(pv, d);
    if (lane == 0) cbsh = pv;
  }
  __syncthreads();  // cbsh ready

  float sbase = (float)(cbsh + wbase + (x - ts));  // exclusive raw-f0 prefix
#pragma unroll
  for (int e = 0; e < EPT; ++e) sv[e] += sbase;    // absolute prefixes

  // ---- per-thread op constants from the shared table ----
  int i0 = ch * CHUNK + t * EPT;
  int i0s = (int)floorf((float)i0 * STEPF);
  float pr0 = (float)i0 * STEPF - (float)i0s;  // local frame coord; seg0 pr<1
  int idx = i0s - i0s_blk;                     // 0..4

  float frs[6], c0[6], s0[6], dd6[6];
#pragma unroll
  for (int k = 0; k < 6; ++k) {
    frs[k] = freq_ratio[row * 6 + k] * (1.0f / 16000.0f);
    float em = emsh[k];
    float E0 = envtab[idx][k], E1 = envtab[idx + 1][k], E2 = envtab[idx + 2][k];
    c0[k] = E0 * em;
    s0[k] = (E1 - E0) * em;
    dd6[k] = (E2 - E1) * em - s0[k];
  }

  auto sin2 = [](v2f x2) -> v2f {
    return (v2f){__builtin_amdgcn_sinf(__builtin_amdgcn_fractf(x2.x)),
                 __builtin_amdgcn_sinf(__builtin_amdgcn_fractf(x2.y))};
  };

  // ---- half-wise packed-f32 FM chain (4 pairs = 8 elements in flight) ----
#pragma unroll
  for (int h = 0; h < 2; ++h) {
    const int b0 = h * 8;
    v2f sv2[4], pr2[4], m2[4], o2[4];
#pragma unroll
    for (int p = 0; p < 4; ++p) {
      sv2[p] = (v2f){sv[b0 + 2 * p], sv[b0 + 2 * p + 1]};
      v2f pr = (v2f){pr0 + (float)(b0 + 2 * p) * STEPF,
                     pr0 + (float)(b0 + 2 * p + 1) * STEPF};
      pr2[p] = pr;
      m2[p] = __builtin_elementwise_max(pr - (v2f){1.0f, 1.0f},
                                        (v2f){0.0f, 0.0f});
    }
    auto env2 = [&](int k, int p) -> v2f {
      return __builtin_elementwise_fma(
          m2[p], (v2f){dd6[k], dd6[k]},
          __builtin_elementwise_fma(pr2[p], (v2f){s0[k], s0[k]},
                                    (v2f){c0[k], c0[k]}));
    };
#pragma unroll
    for (int p = 0; p < 4; ++p)   // op6 (no mod)
      o2[p] = sin2((v2f){frs[5], frs[5]} * sv2[p]) * env2(5, p);
#pragma unroll
    for (int p = 0; p < 4; ++p)   // op5
      o2[p] = sin2(__builtin_elementwise_fma((v2f){frs[4], frs[4]}, sv2[p], o2[p])) * env2(4, p);
#pragma unroll
    for (int p = 0; p < 4; ++p)   // op4
      o2[p] = sin2(__builtin_elementwise_fma((v2f){frs[3], frs[3]}, sv2[p], o2[p])) * env2(3, p);
#pragma unroll
    for (int p = 0; p < 4; ++p)   // op3 (env pre-halved)
      o2[p] = sin2(__builtin_elementwise_fma((v2f){frs[2], frs[2]}, sv2[p], o2[p])) * env2(2, p);
#pragma unroll
    for (int p = 0; p < 4; ++p) { // op2 -> op1 (env pre-halved), add to o3
      v2f q2 = sin2((v2f){frs[1], frs[1]} * sv2[p]) * env2(1, p);
      v2f q1 = sin2(__builtin_elementwise_fma((v2f){frs[0], frs[0]}, sv2[p], q2)) * env2(0, p);
      o2[p] += q1;
    }
    float4 ov;
    ov.x = o2[0].x; ov.y = o2[0].y; ov.z = o2[1].x; ov.w = o2[1].y;
    *(float4*)&tile[swz16(t, b0)] = ov;
    ov.x = o2[2].x; ov.y = o2[2].y; ov.z = o2[3].x; ov.w = o2[3].y;
    *(float4*)&tile[swz16(t, b0 + 4)] = ov;
  }
  __syncthreads();

  // ---- coalesced LDS -> global store ----
  float4* ob = (float4*)(out + rowOff + ch * CHUNK);
#pragma unroll
  for (int i = 0; i < 4; ++i) {
    int li = i * 1024 + t * 4;
    int tt = li >> 4, ee = li & 15;
    ob[i * NTHR + t] = *(const float4*)&tile[swz16(tt, ee)];
  }
}

extern "C" void kernel_launch(void* const* d_in, const int* in_sizes, int n_in,
                              void* d_out, int out_size, void* d_ws, size_t ws_size,
                              hipStream_t stream) {
  const float* mod_index  = (const float*)d_in[0]; // [32,6]
  const float* freq_ratio = (const float*)d_in[1]; // [32,6]
  const float* f0         = (const float*)d_in[2]; // [32,T]
  const float* adsr       = (const float*)d_in[3]; // [32,11]
  float* out = (float*)d_out;

  char* ws = (char*)d_ws;
  unsigned long long* vals = (unsigned long long*)ws;     // 2048 x 256 B
  unsigned int* counter = (unsigned int*)(ws + NBLK * 256);

  // zero vals + counter every launch (in-stream, graph-capturable)
  hipMemsetAsync(ws, 0, WS_CLEAR, stream);
  hipLaunchKernelGGL(k_one, dim3(NBLK), dim3(NTHR), 0, stream,
                     f0, mod_index, freq_ratio, adsr, vals, counter, out);
}

// Round 17
// 24.929 us; speedup vs baseline: 1.9444x; 1.9444x over previous
//
#include <hip/hip_runtime.h>
#include <math.h>

#define B 32
#define T 262144
#define NFR 250
#define NCH 64              // chunks per row
#define CHUNK 4096          // elements per chunk
#define NTHR 256
#define EPT 16              // elements per thread (contiguous ownership)

#define STEPF (249.0f / 262143.0f)  // frame step per sample

typedef float v2f __attribute__((ext_vector_type(2)));
typedef float v4f __attribute__((ext_vector_type(4)));  // for NT stores

// [256][16] f32 tile swizzle: XOR on e bits [3:2] keeps float4 alignment and
// makes per-owner b128 and linear coalesced b128 both bank-conflict-free.
__device__ __forceinline__ int swz16(int t, int e) {
  return t * 16 + (e ^ ((t & 3) << 2));
}

// ---------------- kernel 1: per-chunk f64 sums of f0 (coalesced) ----------------
__global__ __launch_bounds__(NTHR) void k_partial(const float* __restrict__ f0,
                                                  double* __restrict__ partials) {
  int row = blockIdx.y, ch = blockIdx.x, t = threadIdx.x;
  const float4* p = (const float4*)(f0 + (size_t)row * T + ch * CHUNK);
  double s = 0.0;
#pragma unroll
  for (int i = 0; i < CHUNK / 4 / NTHR; ++i) {  // 4 coalesced float4 loads
    float4 v = p[i * NTHR + t];
    s += (double)v.x + (double)v.y + (double)v.z + (double)v.w;
  }
#pragma unroll
  for (int d = 32; d > 0; d >>= 1) s += __shfl_down(s, d);
  __shared__ double wsum[NTHR / 64];
  int lane = t & 63, wid = t >> 6;
  if (lane == 0) wsum[wid] = s;
  __syncthreads();
  if (t == 0) {
    double tot = 0.0;
#pragma unroll
    for (int w = 0; w < NTHR / 64; ++w) tot += wsum[w];
    __hip_atomic_store(&partials[row * NCH + ch], tot, __ATOMIC_RELAXED,
                       __HIP_MEMORY_SCOPE_AGENT);
  }
}

// --- kernel 2: scan + packed-f32 FM chain; NT stores keep f0 in L2 ---
__global__ __launch_bounds__(NTHR, 6) void k_main(const float* __restrict__ f0,
                                                  const float* __restrict__ mod_index,
                                                  const float* __restrict__ freq_ratio,
                                                  const float* __restrict__ adsr,
                                                  const double* __restrict__ partials,
                                                  float* __restrict__ out) {
  __shared__ __align__(16) float tile[NTHR * EPT];  // 16 KB output staging
  __shared__ double wsum[NTHR / 64];
  __shared__ float envtab[8][6];  // raw envelope at frames i0s_blk+0..7, per op
  __shared__ float emsh[6];       // 2*sigmoid(mod_index), pre-halved for k=0,2

  int row = blockIdx.y, ch = blockIdx.x, t = threadIdx.x;
  int lane = t & 63, wid = t >> 6;
  size_t rowOff = (size_t)row * T;

  // ---- issue own 16-element loads first (latency hidden by setup below) ----
  const float4* fp4 = (const float4*)(f0 + rowOff + ch * CHUNK + t * EPT);
  float4 v4[4];
#pragma unroll
  for (int q = 0; q < 4; ++q) v4[q] = fp4[q];

  // ---- chunk base: wave-parallel reduce of preceding chunk sums ----
  double pv = 0.0;
  if (lane < ch)  // NCH=64 fits one 64-lane wave exactly
    pv = __hip_atomic_load(&partials[row * NCH + lane], __ATOMIC_RELAXED,
                           __HIP_MEMORY_SCOPE_AGENT);
#pragma unroll
  for (int d = 32; d > 0; d >>= 1) pv += __shfl_down(pv, d);
  double cbase = __shfl(pv, 0);

  // ---- shared setup: block spans <4 envelope frames -> one table ----
  int i0_blk = ch * CHUNK;
  int i0s_blk = (int)floorf((float)i0_blk * STEPF);
  if (t < 48) {  // raw envelope (no em) at frame i0s_blk + t/6, op t%6
    int fr = t / 6, k = t - 6 * fr;
    int fi = i0s_blk + fr;
    fi = (fi < NFR - 1) ? fi : NFR - 1;
    const float* ap = adsr + row * 11 + k;
    float fl = ap[0], pk = ap[1];
    float a = fmaxf(ap[2], 1e-5f);
    float de = fmaxf(ap[3], 1e-5f);
    float ss = ap[4];
    float r = fmaxf(ap[5], 1e-5f);
    float tt = (float)fi * (1.0f / 249.0f);
    float att = fminf(fmaxf(tt / a, 0.0f), 1.0f);
    float dec = fminf(fmaxf((tt - a) / de, 0.0f), 1.0f);
    float rel = fminf(fmaxf((tt - (1.0f - r)) / r, 0.0f), 1.0f);
    float env = att * (1.0f - (1.0f - ss) * dec) * (1.0f - rel);
    envtab[fr][k] = fl + (pk - fl) * env;
  } else if (t < 54) {
    int k = t - 48;
    float em = 2.0f / (1.0f + expf(-mod_index[row * 6 + k]));
    emsh[k] = (k == 0 || k == 2) ? 0.5f * em : em;  // fold (o3+o1)/2
  }

  // ---- consume loads: relative inclusive prefix ----
  float sv[EPT];
  {
    float a = 0.0f;
#pragma unroll
    for (int q = 0; q < 4; ++q) {
      a += v4[q].x; sv[4 * q] = a;
      a += v4[q].y; sv[4 * q + 1] = a;
      a += v4[q].z; sv[4 * q + 2] = a;
      a += v4[q].w; sv[4 * q + 3] = a;
    }
  }
  double ts = (double)sv[EPT - 1];

  // ---- wave inclusive f64 scan over thread sums ----
  double x = ts;
#pragma unroll
  for (int d = 1; d < 64; d <<= 1) {
    double n = __shfl_up(x, d);
    if (lane >= d) x += n;
  }
  if (lane == 63) wsum[wid] = x;
  __syncthreads();  // wsum + envtab + emsh ready
  double wbase = 0.0;
#pragma unroll
  for (int w = 0; w < NTHR / 64; ++w) wbase += (w < wid) ? wsum[w] : 0.0;
  float sbase = (float)(cbase + wbase + (x - ts));  // exclusive raw-f0 prefix

#pragma unroll
  for (int e = 0; e < EPT; ++e) sv[e] += sbase;  // absolute prefixes

  // ---- per-thread op constants from the shared table ----
  int i0 = ch * CHUNK + t * EPT;
  int i0s = (int)floorf((float)i0 * STEPF);
  float pr0 = (float)i0 * STEPF - (float)i0s;  // local frame coord; seg0 pr<1
  int idx = i0s - i0s_blk;                     // 0..4

  float frs[6], c0[6], s0[6], dd6[6];
#pragma unroll
  for (int k = 0; k < 6; ++k) {
    frs[k] = freq_ratio[row * 6 + k] * (1.0f / 16000.0f);
    float em = emsh[k];
    float E0 = envtab[idx][k], E1 = envtab[idx + 1][k], E2 = envtab[idx + 2][k];
    c0[k] = E0 * em;
    s0[k] = (E1 - E0) * em;
    dd6[k] = (E2 - E1) * em - s0[k];
  }

  auto sin2 = [](v2f x2) -> v2f {
    return (v2f){__builtin_amdgcn_sinf(__builtin_amdgcn_fractf(x2.x)),
                 __builtin_amdgcn_sinf(__builtin_amdgcn_fractf(x2.y))};
  };

  // ---- half-wise packed-f32 FM chain (4 pairs = 8 elements in flight) ----
#pragma unroll
  for (int h = 0; h < 2; ++h) {
    const int b0 = h * 8;
    v2f sv2[4], pr2[4], m2[4], o2[4];
#pragma unroll
    for (int p = 0; p < 4; ++p) {
      sv2[p] = (v2f){sv[b0 + 2 * p], sv[b0 + 2 * p + 1]};
      v2f pr = (v2f){pr0 + (float)(b0 + 2 * p) * STEPF,
                     pr0 + (float)(b0 + 2 * p + 1) * STEPF};
      pr2[p] = pr;
      m2[p] = __builtin_elementwise_max(pr - (v2f){1.0f, 1.0f},
                                        (v2f){0.0f, 0.0f});
    }
    auto env2 = [&](int k, int p) -> v2f {  // 2 pk_fma per pair
      return __builtin_elementwise_fma(
          m2[p], (v2f){dd6[k], dd6[k]},
          __builtin_elementwise_fma(pr2[p], (v2f){s0[k], s0[k]},
                                    (v2f){c0[k], c0[k]}));
    };
#pragma unroll
    for (int p = 0; p < 4; ++p)   // op6 (no mod)
      o2[p] = sin2((v2f){frs[5], frs[5]} * sv2[p]) * env2(5, p);
#pragma unroll
    for (int p = 0; p < 4; ++p)   // op5
      o2[p] = sin2(__builtin_elementwise_fma((v2f){frs[4], frs[4]}, sv2[p], o2[p])) * env2(4, p);
#pragma unroll
    for (int p = 0; p < 4; ++p)   // op4
      o2[p] = sin2(__builtin_elementwise_fma((v2f){frs[3], frs[3]}, sv2[p], o2[p])) * env2(3, p);
#pragma unroll
    for (int p = 0; p < 4; ++p)   // op3 (env pre-halved)
      o2[p] = sin2(__builtin_elementwise_fma((v2f){frs[2], frs[2]}, sv2[p], o2[p])) * env2(2, p);
#pragma unroll
    for (int p = 0; p < 4; ++p) { // op2 -> op1 (env pre-halved), add to o3
      v2f q2 = sin2((v2f){frs[1], frs[1]} * sv2[p]) * env2(1, p);
      v2f q1 = sin2(__builtin_elementwise_fma((v2f){frs[0], frs[0]}, sv2[p], q2)) * env2(0, p);
      o2[p] += q1;
    }
    // stage this half into own LDS slots
    float4 ov;
    ov.x = o2[0].x; ov.y = o2[0].y; ov.z = o2[1].x; ov.w = o2[1].y;
    *(float4*)&tile[swz16(t, b0)] = ov;
    ov.x = o2[2].x; ov.y = o2[2].y; ov.z = o2[3].x; ov.w = o2[3].y;
    *(float4*)&tile[swz16(t, b0 + 4)] = ov;
  }
  __syncthreads();

  // ---- coalesced LDS -> global store (non-temporal: out is never re-read,
  //      and bypassing L2 preserves the k_partial-warmed f0 lines) ----
  v4f* ob = (v4f*)(out + rowOff + ch * CHUNK);
#pragma unroll
  for (int i = 0; i < 4; ++i) {
    int li = i * 1024 + t * 4;
    int tt = li >> 4, ee = li & 15;
    __builtin_nontemporal_store(*(const v4f*)&tile[swz16(tt, ee)],
                                ob + i * NTHR + t);
  }
}

extern "C" void kernel_launch(void* const* d_in, const int* in_sizes, int n_in,
                              void* d_out, int out_size, void* d_ws, size_t ws_size,
                              hipStream_t stream) {
  const float* mod_index  = (const float*)d_in[0]; // [32,6]
  const float* freq_ratio = (const float*)d_in[1]; // [32,6]
  const float* f0         = (const float*)d_in[2]; // [32,T]
  const float* adsr       = (const float*)d_in[3]; // [32,11]
  float* out = (float*)d_out;

  double* partials = (double*)d_ws;  // 32*64*8 = 16384 bytes

  hipLaunchKernelGGL(k_partial, dim3(NCH, B), dim3(NTHR), 0, stream, f0, partials);
  hipLaunchKernelGGL(k_main, dim3(NCH, B), dim3(NTHR), 0, stream,
                     f0, mod_index, freq_ratio, adsr, partials, out);
}